// Round 1
// 535.208 us; speedup vs baseline: 1.0413x; 1.0413x over previous
//
#include <hip/hip_runtime.h>
#include <math.h>

#define HID   128
#define MAXN  100000
#define MAXE  300000
#define EVT   4096
#define NNODE 20000
#define NEDGE 320000

typedef unsigned short u16;
typedef __attribute__((ext_vector_type(8))) short bf16x8;
typedef __attribute__((ext_vector_type(4))) float f32x4;

// ---------------- workspace layout (bytes) ----------------
// PERSIST (weights, live for whole launch)
#define OFF_WIHB      0u            // 384*640 bf16
#define OFF_WHHB      491520u      // 384*128 bf16
#define OFF_WEB       589824u      // 128*256 bf16
#define OFF_WALLB     655360u      // 768*128 bf16
#define OFF_BALL      851968u      // 768 f32
#define BASE2         855040u
// EVENT arena (from BASE2)
#define OFF_REP_SRC   (BASE2 + 0u)
#define OFF_REP_DST   (BASE2 + 400128u)
#define OFF_CNT_SRC   (BASE2 + 800256u)
#define OFF_CNT_DST   (BASE2 + 1200384u)
#define OFF_SUM_SRC   (BASE2 + 1600512u)    // 4096*640 f32
#define OFF_SUM_DST   (BASE2 + 12086272u)   // 4096*640 f32
#define OFF_XGB       (BASE2 + 22572032u)   // 8192*640 bf16
#define OFF_HG        (BASE2 + 33057792u)   // 8192*128 f32
#define OFF_HGB       (BASE2 + 37252096u)   // 8192*128 bf16
#define OFF_GI        (BASE2 + 39349248u)   // 8192*384 f32
#define OFF_GH        (BASE2 + 51932160u)   // 8192*384 f32
#define OFF_NEWMEM    (BASE2 + 64515072u)   // (unused now)
// NODE arena (aliases EVENT arena; event phase fully complete first)
#define OFF_XB        (BASE2 + 0u)          // 20000*128 bf16
#define OFF_QKVSE     (BASE2 + 5120000u)    // 20000*768 f32
#define OFF_KVB       (BASE2 + 66560000u)   // 20000*256 bf16
#define OFF_DEG       (BASE2 + 76800000u)   // 20000 i32
#define OFF_OFFS      (BASE2 + 76880128u)   // 20001 i32
#define OFF_CURSOR    (BASE2 + 76960256u)   // 20000 i32
#define OFF_BSUM      (BASE2 + 77040384u)   // (unused now)
#define OFF_SORTED    (BASE2 + 77041664u)   // 320000 i32
#define OFF_SACCB     (BASE2 + 78321664u)   // 20000*256 bf16
// peak ~89.4 MB

__device__ __forceinline__ float sigmoidf_(float x) { return 1.f / (1.f + __expf(-x)); }
__device__ __forceinline__ u16 f2b(float f) {
    unsigned u = __float_as_uint(f);
    unsigned r = (u + 0x7fffu + ((u >> 16) & 1u)) >> 16;
    return (u16)r;
}
__device__ __forceinline__ float b2f(unsigned h) { return __uint_as_float(h << 16); }

// ---- fused weight prep: 3 bf16 converts + Wall build + deg zero (one dispatch) ----
__global__ void k_prep(const float* __restrict__ w_ih, const float* __restrict__ w_hh,
                       const float* __restrict__ we,
                       const float* __restrict__ wq, const float* __restrict__ wk_,
                       const float* __restrict__ wv, const float* __restrict__ wskip,
                       const float* __restrict__ bq, const float* __restrict__ bk,
                       const float* __restrict__ bv, const float* __restrict__ bskip,
                       u16* __restrict__ w_ih_b, u16* __restrict__ w_hh_b,
                       u16* __restrict__ we_b, u16* __restrict__ Wallb,
                       float* __restrict__ ball, int* __restrict__ deg) {
    int b = blockIdx.x, t = threadIdx.x;
    if (b < 960) {                      // w_ih: 384*640 = 960*256
        int i = b * 256 + t;
        w_ih_b[i] = f2b(w_ih[i]);
        return;
    }
    b -= 960;
    if (b < 192) {                      // w_hh: 384*128 = 192*256
        int i = b * 256 + t;
        w_hh_b[i] = f2b(w_hh[i]);
        return;
    }
    b -= 192;
    if (b < 128) {                      // we: 128*256 = 128*256
        int i = b * 256 + t;
        we_b[i] = f2b(we[i]);
        return;
    }
    b -= 128;
    if (b < 79) {                       // deg zero (20000 ints)
        int i = b * 256 + t;
        if (i < NNODE) deg[i] = 0;
        return;
    }
    b -= 79;
    // Wall build: b in [0,384), idx over 768*128
    int idx = b * 256 + t;
    int row = idx >> 7;
    int k = idx & 127;
    float v;
    if (row < 128)      v = wq[row * 128 + k];
    else if (row < 256) v = wk_[(row - 128) * 128 + k];
    else if (row < 384) v = wv[(row - 256) * 128 + k];
    else if (row < 512) v = wskip[(row - 384) * 128 + k];
    else {
        int j = row - 512;
        float a = 0.f;
        for (int t2 = 0; t2 < 128; t2++) a += wq[t2 * 128 + k] * we[t2 * 256 + j];
        v = a;
    }
    Wallb[row * 128 + k] = f2b(v);
    if (k == 0) {
        float bb;
        if (row < 128)      bb = bq[row];
        else if (row < 256) bb = bk[row - 128];
        else if (row < 384) bb = bv[row - 256];
        else if (row < 512) bb = bskip[row - 384];
        else { int j = row - 512; float a = 0.f; for (int t2 = 0; t2 < 128; t2++) a += bq[t2] * we[t2 * 256 + j]; bb = a; }
        ball[row] = bb;
    }
}

// ---- fused clears: rep (0xFF, 800256 B) + cnt+sums (0, contiguous 21.77 MB) ----
__global__ void k_zero(char* __restrict__ base) {
    const int NFF = 50016;     // 800256/16
    const int NZ  = 1360736;   // (800256 + 20971520)/16
    uint4 ff = make_uint4(0xFFFFFFFFu, 0xFFFFFFFFu, 0xFFFFFFFFu, 0xFFFFFFFFu);
    uint4 zz = make_uint4(0u, 0u, 0u, 0u);
    int idx = blockIdx.x * blockDim.x + threadIdx.x;
    int stride = gridDim.x * blockDim.x;
    uint4* pff = (uint4*)base;                 // rep_src + rep_dst
    uint4* pzz = (uint4*)(base + 800256);      // cnt_src + cnt_dst + sum_src + sum_dst
    for (int i = idx; i < NFF; i += stride) pff[i] = ff;
    for (int i = idx; i < NZ; i += stride) pzz[i] = zz;
}

// ---- fused rep/count tables + dst-degree histogram ----
__global__ void k_tables_deg(const int* __restrict__ src_ids, const int* __restrict__ dst_ids,
                             unsigned* rep_src, unsigned* rep_dst, int* cnt_src, int* cnt_dst,
                             const int* __restrict__ eidx, int* __restrict__ deg) {
    int b = blockIdx.x, t = threadIdx.x;
    if (b < 16) {
        int i = b * 256 + t;
        if (i >= EVT) return;
        int s = src_ids[i], d = dst_ids[i];
        atomicMin(&rep_src[s], (unsigned)i);
        atomicAdd(&cnt_src[s], 1);
        atomicMin(&rep_dst[d], (unsigned)i);
        atomicAdd(&cnt_dst[d], 1);
    } else {
        int j = (b - 16) * 256 + t;
        if (j >= NEDGE) return;
        atomicAdd(&deg[eidx[NEDGE + j]], 1);
    }
}

// ---- build messages and aggregate into per-rep sums (fast path when unique) ----
__global__ void k_message(const int* __restrict__ et_ids, const int* __restrict__ src_ids,
                          const float* __restrict__ src_mask, const int* __restrict__ dst_ids,
                          const float* __restrict__ dst_mask, const int* __restrict__ ev_eids,
                          const float* __restrict__ ev_emb, const float* __restrict__ ev_mask,
                          const float* __restrict__ ev_ts, const float* __restrict__ memory,
                          const float* __restrict__ last_update, const float* __restrict__ time_w,
                          const float* __restrict__ time_b, const unsigned* __restrict__ rep_src,
                          const unsigned* __restrict__ rep_dst, const int* __restrict__ cnt_src,
                          const int* __restrict__ cnt_dst, float* sum_src, float* sum_dst) {
    int i = blockIdx.x;
    int c = threadIdx.x;
    int et = et_ids[i];
    float sm = src_mask[i], dm = dst_mask[i], em = ev_mask[i], ts = ev_ts[i];
    int sid = src_ids[i], did = dst_ids[i], eid = ev_eids[i];
    float isnode = (et == 3 || et == 4) ? 1.f : 0.f;
    float rel = ts - last_update[eid] * dm;
    float tval = ts * isnode + rel * dm;
    float tse = __cosf(tval * time_w[c] + time_b[c]) * em;
    float typ = (float)et;
    float sv = memory[(size_t)sid * HID + c] * sm;
    float dv = memory[(size_t)did * HID + c] * dm;
    float ev = ev_emb[(size_t)i * HID + c];
    float* ps = sum_src + (size_t)rep_src[sid] * 640;
    if (cnt_src[sid] == 1) {
        ps[c] = typ * em; ps[128 + c] = sv * em; ps[256 + c] = dv * em;
        ps[384 + c] = tse * em; ps[512 + c] = ev * em;
    } else {
        atomicAdd(ps + c, typ * em);
        atomicAdd(ps + 128 + c, sv * em);
        atomicAdd(ps + 256 + c, dv * em);
        atomicAdd(ps + 384 + c, tse * em);
        atomicAdd(ps + 512 + c, ev * em);
    }
    float* pd = sum_dst + (size_t)rep_dst[did] * 640;
    if (cnt_dst[did] == 1) {
        pd[c] = typ * dm; pd[128 + c] = dv * dm; pd[256 + c] = sv * dm;
        pd[384 + c] = tse * dm; pd[512 + c] = ev * dm;
    } else {
        atomicAdd(pd + c, typ * dm);
        atomicAdd(pd + 128 + c, dv * dm);
        atomicAdd(pd + 256 + c, sv * dm);
        atomicAdd(pd + 384 + c, tse * dm);
        atomicAdd(pd + 512 + c, ev * dm);
    }
}

// ---- fused gather: Xg (y<5) and Hg/Hgb (y==5) ----
__global__ void k_build(const int* __restrict__ src_ids, const int* __restrict__ dst_ids,
                        const unsigned* __restrict__ rep_src, const unsigned* __restrict__ rep_dst,
                        const int* __restrict__ cnt_src, const int* __restrict__ cnt_dst,
                        const float* __restrict__ sum_src, const float* __restrict__ sum_dst,
                        const float* __restrict__ memory, u16* __restrict__ Xgb,
                        float* __restrict__ Hg, u16* __restrict__ Hgb) {
    int r = blockIdx.x, y = blockIdx.y, t = threadIdx.x;
    if (y == 5) {
        int id = (r < EVT) ? src_ids[r] : dst_ids[r - EVT];
        float v = memory[(size_t)id * HID + t];
        Hg[(size_t)r * HID + t] = v;
        Hgb[(size_t)r * HID + t] = f2b(v);
        return;
    }
    int c = y * 128 + t;
    float v;
    if (r < EVT) {
        int id = src_ids[r];
        int cnt = cnt_src[id]; if (cnt < 1) cnt = 1;
        v = sum_src[(size_t)rep_src[id] * 640 + c] / (float)cnt;
    } else {
        int id = dst_ids[r - EVT];
        int cnt = cnt_dst[id]; if (cnt < 1) cnt = 1;
        v = sum_dst[(size_t)rep_dst[id] * 640 + c] / (float)cnt;
    }
    Xgb[(size_t)r * 640 + c] = f2b(v);
}

// ---- MFMA bf16 GEMM tile body: C[M,N] (+)= A[M,K] @ W[N,K]^T (+bias) ----
// 128x128 tile, 256 threads (4 waves, each 64x64), BK=32, mfma_f32_16x16x32_bf16.
// When KVb != nullptr, cols 128..384 are emitted ONLY as bf16 (f32 store is dead).
__device__ __forceinline__ void gemm_tile(const u16* __restrict__ A, const u16* __restrict__ W,
                                          const float* __restrict__ bias, float* __restrict__ C,
                                          u16* __restrict__ KVb, int M, int N, int K, int acc,
                                          u16* Als, u16* Wls) {
    int tid = threadIdx.x;
    int bm = blockIdx.x * 128, bn = blockIdx.y * 128;
    int wave = tid >> 6, lane = tid & 63;
    int wm = (wave & 1) * 64, wn = (wave >> 1) * 64;
    int l15 = lane & 15, quad = lane >> 4;
    f32x4 accf[4][4] = {};
    for (int k0 = 0; k0 < K; k0 += 32) {
#pragma unroll
        for (int h = 0; h < 2; ++h) {
            int ch = tid + h * 256;
            int row = ch >> 2, kc = (ch & 3) * 8;
            int gr = bm + row;
            float4 av = make_float4(0.f, 0.f, 0.f, 0.f);
            if (gr < M) av = *(const float4*)(A + (size_t)gr * K + k0 + kc);
            *(float4*)&Als[row * 40 + kc] = av;
            int wr = bn + row;
            float4 wv_ = *(const float4*)(W + (size_t)wr * K + k0 + kc);
            *(float4*)&Wls[row * 40 + kc] = wv_;
        }
        __syncthreads();
        bf16x8 af[4], bfr[4];
#pragma unroll
        for (int r = 0; r < 4; ++r)
            af[r] = *(const bf16x8*)&Als[(wm + r * 16 + l15) * 40 + quad * 8];
#pragma unroll
        for (int c2 = 0; c2 < 4; ++c2)
            bfr[c2] = *(const bf16x8*)&Wls[(wn + c2 * 16 + l15) * 40 + quad * 8];
#pragma unroll
        for (int r = 0; r < 4; ++r)
#pragma unroll
            for (int c2 = 0; c2 < 4; ++c2)
                accf[r][c2] = __builtin_amdgcn_mfma_f32_16x16x32_bf16(af[r], bfr[c2], accf[r][c2], 0, 0, 0);
        __syncthreads();
    }
#pragma unroll
    for (int r = 0; r < 4; ++r) {
#pragma unroll
        for (int c2 = 0; c2 < 4; ++c2) {
            int ncol = bn + wn + c2 * 16 + l15;
            float bv = bias ? bias[ncol] : 0.f;
#pragma unroll
            for (int reg = 0; reg < 4; ++reg) {
                int mrow = bm + wm + r * 16 + quad * 4 + reg;
                if (mrow >= M) continue;
                float v = accf[r][c2][reg] + bv;
                if (KVb && ncol >= 128 && ncol < 384) {
                    KVb[(size_t)mrow * 256 + (ncol - 128)] = f2b(v);
                } else {
                    if (acc) v += C[(size_t)mrow * N + ncol];
                    C[(size_t)mrow * N + ncol] = v;
                }
            }
        }
    }
}

__global__ __launch_bounds__(256) void k_gemm_mfma(const u16* __restrict__ A,
                                                   const u16* __restrict__ W,
                                                   const float* __restrict__ bias,
                                                   float* __restrict__ C,
                                                   u16* __restrict__ KVb,
                                                   int M, int N, int K, int acc) {
    __shared__ u16 Als[128 * 40];
    __shared__ u16 Wls[128 * 40];
    gemm_tile(A, W, bias, C, KVb, M, N, K, acc, Als, Wls);
}

// ---- fused event GEMMs: z=0 -> Gi (K=640), z=1 -> Gh (K=128) ----
__global__ __launch_bounds__(256) void k_gemm_dual(const u16* __restrict__ A0, const u16* __restrict__ W0,
                                                   const float* __restrict__ b0, float* __restrict__ C0,
                                                   const u16* __restrict__ A1, const u16* __restrict__ W1,
                                                   const float* __restrict__ b1, float* __restrict__ C1) {
    __shared__ u16 Als[128 * 40];
    __shared__ u16 Wls[128 * 40];
    if (blockIdx.z == 0) gemm_tile(A0, W0, b0, C0, nullptr, 2 * EVT, 384, 640, 0, Als, Wls);
    else                 gemm_tile(A1, W1, b1, C1, nullptr, 2 * EVT, 384, 128, 0, Als, Wls);
}

// ---- fused GRU gate combine + scatter-to-memory (dst overrides src) ----
// Reference semantics: memory[src_ids] = new_src; then memory[dst_ids] = new_dst.
// So a src-row write is only visible if its id never appears as a dst id
// (rep_dst[id] == ~0u). Duplicates within a side carry identical values.
__global__ void k_gru_scatter(const float* __restrict__ Gi, const float* __restrict__ Gh,
                              const float* __restrict__ Hg, const int* __restrict__ src_ids,
                              const int* __restrict__ dst_ids, const unsigned* __restrict__ rep_dst,
                              float* __restrict__ memory) {
    int r = blockIdx.x, c = threadIdx.x;
    const float* gi = Gi + (size_t)r * 384;
    const float* gh = Gh + (size_t)r * 384;
    float rg = sigmoidf_(gi[c] + gh[c]);
    float z  = sigmoidf_(gi[128 + c] + gh[128 + c]);
    float n  = tanhf(gi[256 + c] + rg * gh[256 + c]);
    float h0 = Hg[(size_t)r * HID + c];
    float h  = (1.f - z) * n + z * h0;
    if (r < EVT) {
        int sid = src_ids[r];
        if (rep_dst[sid] == 0xFFFFFFFFu) memory[(size_t)sid * HID + c] = h;
    } else {
        int did = dst_ids[r - EVT];
        memory[(size_t)did * HID + c] = h;
    }
}

__global__ void k_x(const int* __restrict__ node_ids, const float* __restrict__ nf,
                    const float* __restrict__ memory, u16* __restrict__ Xb) {
    int p = blockIdx.x, c = threadIdx.x;
    int nid = node_ids[p];
    Xb[(size_t)p * HID + c] = f2b(nf[(size_t)nid * HID + c] + memory[(size_t)nid * HID + c]);
}

// ---- single-block exclusive scan over 20000 degrees ----
__global__ __launch_bounds__(1024) void k_scan_one(const int* __restrict__ deg,
                                                   int* __restrict__ offs, int* __restrict__ cursor) {
    __shared__ int wsum[16];
    int t = threadIdx.x, lane = t & 63, w = t >> 6;
    int carry = 0;
    for (int base = 0; base < NNODE; base += 1024) {
        int i = base + t;
        int v = (i < NNODE) ? deg[i] : 0;
        int x = v;
#pragma unroll
        for (int d = 1; d < 64; d <<= 1) { int y = __shfl_up(x, d, 64); if (lane >= d) x += y; }
        if (lane == 63) wsum[w] = x;
        __syncthreads();
        int add = 0, tot = 0;
        for (int k2 = 0; k2 < 16; ++k2) { int s = wsum[k2]; if (k2 < w) add += s; tot += s; }
        if (i < NNODE) { int e = carry + add + x - v; offs[i] = e; cursor[i] = e; }
        carry += tot;
        __syncthreads();
    }
    if (t == 0) offs[NNODE] = NEDGE;
}

__global__ void k_sortscat(const int* __restrict__ eidx, int* __restrict__ cursor,
                           int* __restrict__ sorted) {
    int j = blockIdx.x * blockDim.x + threadIdx.x;
    if (j >= NEDGE) return;
    int d = eidx[NEDGE + j];
    int pos = atomicAdd(&cursor[d], 1);
    sorted[pos] = j;
}

// ---- fused per-node attention: 4-edge batched online softmax ----
__global__ __launch_bounds__(256) void k_node(const float* __restrict__ QK,
        const u16* __restrict__ KVb, const int* __restrict__ offs,
        const int* __restrict__ sorted, const int* __restrict__ eidx,
        const int* __restrict__ edge_ids, const float* __restrict__ last_update,
        const float* __restrict__ time_w, const float* __restrict__ time_b,
        const float* __restrict__ ef, const int* __restrict__ tptr,
        float* __restrict__ out, u16* __restrict__ saccb) {
    int wave = threadIdx.x >> 6, lane = threadIdx.x & 63;
    int n = blockIdx.x * 4 + wave;
    int c = 2 * lane;
    const float* base = QK + (size_t)n * 768;
    float2 qd   = *(const float2*)(base + c);
    float2 skip = *(const float2*)(base + 384 + c);
    float2 qet  = *(const float2*)(base + 512 + c);
    float2 qef  = *(const float2*)(base + 640 + c);
    float2 tw   = *(const float2*)(time_w + c);
    float2 tb   = *(const float2*)(time_b + c);
    float tf = (float)(*tptr);
    int start = offs[n], end = offs[n + 1];
    int deg = end - start;
    if (deg == 0) {
        *(float2*)(out + (size_t)n * HID + c) = skip;
        *(unsigned*)(saccb + (size_t)n * 256 + c) = 0u;
        *(unsigned*)(saccb + (size_t)n * 256 + 128 + c) = 0u;
        return;
    }
    float m = -1e30f, l_ = 0.f;
    float va0 = 0.f, va1 = 0.f, s00 = 0.f, s01 = 0.f, s10 = 0.f, s11 = 0.f;
    for (int cb = start; cb < end; cb += 64) {
        int cnt = end - cb; if (cnt > 64) cnt = 64;
        int s_l = 0, eid_l = 0; float rt_l = 0.f;
        if (lane < cnt) {
            int j = sorted[cb + lane];
            s_l = eidx[j];
            eid_l = edge_ids[j];
            rt_l = tf - last_update[eid_l];
        }
        for (int e0 = 0; e0 < cnt; e0 += 4) {
            float pv[4], cv0[4], cv1[4], vx[4], vy[4], ex[4], ey[4];
#pragma unroll
            for (int i = 0; i < 4; ++i) {
                int idx = e0 + i;
                int sel = (idx < cnt) ? idx : e0;
                int s   = __shfl(s_l, sel, 64);
                int eid = __shfl(eid_l, sel, 64);
                float rt = __shfl(rt_l, sel, 64);
                unsigned kvp = *(const unsigned*)(KVb + (size_t)s * 256 + c);
                unsigned vvp = *(const unsigned*)(KVb + (size_t)s * 256 + 128 + c);
                float2 ev = *(const float2*)(ef + (size_t)eid * HID + c);
                float k0f = b2f(kvp & 0xffffu), k1f = b2f(kvp >> 16);
                vx[i] = b2f(vvp & 0xffffu); vy[i] = b2f(vvp >> 16);
                cv0[i] = __cosf(rt * tw.x + tb.x);
                cv1[i] = __cosf(rt * tw.y + tb.y);
                ex[i] = ev.x; ey[i] = ev.y;
                pv[i] = qd.x * k0f + qd.y * k1f + qet.x * cv0[i] + qet.y * cv1[i]
                      + qef.x * ev.x + qef.y * ev.y;
            }
#pragma unroll
            for (int msk = 32; msk > 0; msk >>= 1) {
#pragma unroll
                for (int i = 0; i < 4; ++i) pv[i] += __shfl_xor(pv[i], msk, 64);
            }
            float al[4];
#pragma unroll
            for (int i = 0; i < 4; ++i)
                al[i] = (e0 + i < cnt) ? pv[i] * 0.08838834764831845f : -1e30f;
            float gm = fmaxf(fmaxf(al[0], al[1]), fmaxf(al[2], al[3]));
            if (gm > m) {
                float fac = __expf(m - gm);
                l_ *= fac; va0 *= fac; va1 *= fac;
                s00 *= fac; s01 *= fac; s10 *= fac; s11 *= fac;
                m = gm;
            }
#pragma unroll
            for (int i = 0; i < 4; ++i) {
                float w = __expf(al[i] - m);
                l_ += w;
                va0 += w * vx[i]; va1 += w * vy[i];
                s00 += w * cv0[i]; s01 += w * cv1[i];
                s10 += w * ex[i]; s11 += w * ey[i];
            }
        }
    }
    float inv = 1.f / fmaxf(l_, 1e-16f);
    float2 o; o.x = va0 * inv + skip.x; o.y = va1 * inv + skip.y;
    *(float2*)(out + (size_t)n * HID + c) = o;
    unsigned p0 = (unsigned)f2b(s00 * inv) | ((unsigned)f2b(s01 * inv) << 16);
    unsigned p1 = (unsigned)f2b(s10 * inv) | ((unsigned)f2b(s11 * inv) << 16);
    *(unsigned*)(saccb + (size_t)n * 256 + c) = p0;
    *(unsigned*)(saccb + (size_t)n * 256 + 128 + c) = p1;
}

extern "C" void kernel_launch(void* const* d_in, const int* in_sizes, int n_in,
                              void* d_out, int out_size, void* d_ws, size_t ws_size,
                              hipStream_t stream) {
    const int*   et_ids        = (const int*)d_in[0];
    const int*   src_ids       = (const int*)d_in[1];
    const float* src_mask      = (const float*)d_in[2];
    const int*   dst_ids       = (const int*)d_in[3];
    const float* dst_mask      = (const float*)d_in[4];
    const int*   ev_eids       = (const int*)d_in[5];
    const float* ev_emb        = (const float*)d_in[6];
    const float* ev_mask       = (const float*)d_in[7];
    const float* ev_ts         = (const float*)d_in[8];
    const int*   node_ids      = (const int*)d_in[9];
    const int*   edge_ids      = (const int*)d_in[10];
    const int*   edge_index    = (const int*)d_in[11];
    const int*   tptr          = (const int*)d_in[12];
    float*       memory        = (float*)d_in[13];
    const float* last_update   = (const float*)d_in[14];
    const float* node_features = (const float*)d_in[15];
    const float* edge_features = (const float*)d_in[16];
    const float* time_w        = (const float*)d_in[17];
    const float* time_b        = (const float*)d_in[18];
    const float* w_ih          = (const float*)d_in[19];
    const float* w_hh          = (const float*)d_in[20];
    const float* b_ih          = (const float*)d_in[21];
    const float* b_hh          = (const float*)d_in[22];
    const float* wq            = (const float*)d_in[23];
    const float* bq            = (const float*)d_in[24];
    const float* wk            = (const float*)d_in[25];
    const float* bk            = (const float*)d_in[26];
    const float* wv            = (const float*)d_in[27];
    const float* bv            = (const float*)d_in[28];
    const float* we            = (const float*)d_in[29];
    const float* wskip         = (const float*)d_in[30];
    const float* bskip         = (const float*)d_in[31];
    float* out = (float*)d_out;
    char*  wsb = (char*)d_ws;

    u16*   w_ih_b  = (u16*)(wsb + OFF_WIHB);
    u16*   w_hh_b  = (u16*)(wsb + OFF_WHHB);
    u16*   we_b    = (u16*)(wsb + OFF_WEB);
    u16*   Wallb   = (u16*)(wsb + OFF_WALLB);
    float* ball    = (float*)(wsb + OFF_BALL);
    unsigned* rep_src = (unsigned*)(wsb + OFF_REP_SRC);
    unsigned* rep_dst = (unsigned*)(wsb + OFF_REP_DST);
    int*   cnt_src = (int*)(wsb + OFF_CNT_SRC);
    int*   cnt_dst = (int*)(wsb + OFF_CNT_DST);
    float* sum_src = (float*)(wsb + OFF_SUM_SRC);
    float* sum_dst = (float*)(wsb + OFF_SUM_DST);
    u16*   Xgb     = (u16*)(wsb + OFF_XGB);
    float* Hg      = (float*)(wsb + OFF_HG);
    u16*   Hgb     = (u16*)(wsb + OFF_HGB);
    float* Gi      = (float*)(wsb + OFF_GI);
    float* Gh      = (float*)(wsb + OFF_GH);
    u16*   Xb      = (u16*)(wsb + OFF_XB);
    float* QKVSE   = (float*)(wsb + OFF_QKVSE);
    u16*   KVb     = (u16*)(wsb + OFF_KVB);
    int*   deg     = (int*)(wsb + OFF_DEG);
    int*   offs    = (int*)(wsb + OFF_OFFS);
    int*   cursor  = (int*)(wsb + OFF_CURSOR);
    int*   sorted  = (int*)(wsb + OFF_SORTED);
    u16*   saccb   = (u16*)(wsb + OFF_SACCB);

    // ---- weight prep + deg zero (1 dispatch) ----
    k_prep<<<1743, 256, 0, stream>>>(w_ih, w_hh, we, wq, wk, wv, wskip, bq, bk, bv, bskip,
                                     w_ih_b, w_hh_b, we_b, Wallb, ball, deg);
    // ---- event-phase clears (1 dispatch, replaces 3 memsets) ----
    k_zero<<<2048, 256, 0, stream>>>(wsb + OFF_REP_SRC);
    // ---- event phase ----
    k_tables_deg<<<1266, 256, 0, stream>>>(src_ids, dst_ids, rep_src, rep_dst, cnt_src, cnt_dst,
                                           edge_index, deg);
    k_message<<<EVT, 128, 0, stream>>>(et_ids, src_ids, src_mask, dst_ids, dst_mask, ev_eids,
                                       ev_emb, ev_mask, ev_ts, memory, last_update, time_w, time_b,
                                       rep_src, rep_dst, cnt_src, cnt_dst, sum_src, sum_dst);
    k_build<<<dim3(2 * EVT, 6), 128, 0, stream>>>(src_ids, dst_ids, rep_src, rep_dst,
                                                  cnt_src, cnt_dst, sum_src, sum_dst,
                                                  memory, Xgb, Hg, Hgb);
    k_gemm_dual<<<dim3(64, 3, 2), 256, 0, stream>>>(Xgb, w_ih_b, b_ih, Gi,
                                                    Hgb, w_hh_b, b_hh, Gh);
    k_gru_scatter<<<2 * EVT, 128, 0, stream>>>(Gi, Gh, Hg, src_ids, dst_ids, rep_dst, memory);

    // ---- node phase ----
    k_x<<<NNODE, 128, 0, stream>>>(node_ids, node_features, memory, Xb);
    k_gemm_mfma<<<dim3(157, 6), 256, 0, stream>>>(Xb, Wallb, ball, QKVSE, KVb, NNODE, 768, 128, 0);
    k_scan_one<<<1, 1024, 0, stream>>>(deg, offs, cursor);
    k_sortscat<<<1250, 256, 0, stream>>>(edge_index, cursor, sorted);
    k_node<<<NNODE / 4, 256, 0, stream>>>(QKVSE, KVb, offs, sorted, edge_index, edge_ids,
                                          last_update, time_w, time_b, edge_features, tptr,
                                          out, saccb);
    k_gemm_mfma<<<dim3(157, 1), 256, 0, stream>>>(saccb, we_b, nullptr, out, nullptr, NNODE, 128, 256, 1);
}

// Round 2
// 509.975 us; speedup vs baseline: 1.0928x; 1.0495x over previous
//
#include <hip/hip_runtime.h>
#include <math.h>

#define HID   128
#define MAXN  100000
#define MAXE  300000
#define EVT   4096
#define NNODE 20000
#define NEDGE 320000

typedef unsigned short u16;
typedef __attribute__((ext_vector_type(8))) short bf16x8;
typedef __attribute__((ext_vector_type(4))) float f32x4;

// ---------------- workspace layout (bytes) ----------------
// PERSIST (weights, live for whole launch)
#define OFF_WIHB      0u            // 384*640 bf16
#define OFF_WHHB      491520u      // 384*128 bf16
#define OFF_WEB       589824u      // 128*256 bf16
#define OFF_WALLB     655360u      // 768*128 bf16
#define OFF_BALL      851968u      // 768 f32
#define BASE2         855040u
// EVENT arena (from BASE2)
#define OFF_REP_SRC   (BASE2 + 0u)
#define OFF_REP_DST   (BASE2 + 400128u)
#define OFF_CNT_SRC   (BASE2 + 800256u)
#define OFF_CNT_DST   (BASE2 + 1200384u)
#define OFF_SUM_SRC   (BASE2 + 1600512u)    // 4096*640 f32
#define OFF_SUM_DST   (BASE2 + 12086272u)   // 4096*640 f32
#define OFF_XGB       (BASE2 + 22572032u)   // 8192*640 bf16
#define OFF_HG        (BASE2 + 33057792u)   // 8192*128 f32
#define OFF_HGB       (BASE2 + 37252096u)   // 8192*128 bf16
#define OFF_GI        (BASE2 + 39349248u)   // 8192*384 f32
#define OFF_GH        (BASE2 + 51932160u)   // 8192*384 f32
// NODE arena (aliases EVENT arena; event phase fully complete first)
#define OFF_XB        (BASE2 + 0u)          // 20000*128 bf16
#define OFF_QKVSE     (BASE2 + 5120000u)    // 20000*768 f32
#define OFF_KVB       (BASE2 + 66560000u)   // 20000*256 bf16
#define OFF_DEG       (BASE2 + 76800000u)   // 20000 i32
#define OFF_OFFS      (BASE2 + 76880128u)   // 20001 i32
#define OFF_CURSOR    (BASE2 + 76960256u)   // 20000 i32
#define OFF_SORTED    (BASE2 + 77041664u)   // 320000 i32
#define OFF_SACCB     (BASE2 + 78321664u)   // 20000*256 bf16
// peak ~89.4 MB

__device__ __forceinline__ float sigmoidf_(float x) { return 1.f / (1.f + __expf(-x)); }
__device__ __forceinline__ u16 f2b(float f) {
    unsigned u = __float_as_uint(f);
    unsigned r = (u + 0x7fffu + ((u >> 16) & 1u)) >> 16;
    return (u16)r;
}
__device__ __forceinline__ float b2f(unsigned h) { return __uint_as_float(h << 16); }

// ---- fused weight prep: 3 bf16 converts + Wall build + deg zero + arena clears ----
// sections: [0,960) w_ih | [960,1152) w_hh | [1152,1280) we | [1280,1359) deg
//           [1359,1743) Wall | [1743,2767) rep-fill + cnt/sum-zero (grid-stride)
__global__ void k_prep(const float* __restrict__ w_ih, const float* __restrict__ w_hh,
                       const float* __restrict__ we,
                       const float* __restrict__ wq, const float* __restrict__ wk_,
                       const float* __restrict__ wv, const float* __restrict__ wskip,
                       const float* __restrict__ bq, const float* __restrict__ bk,
                       const float* __restrict__ bv, const float* __restrict__ bskip,
                       u16* __restrict__ w_ih_b, u16* __restrict__ w_hh_b,
                       u16* __restrict__ we_b, u16* __restrict__ Wallb,
                       float* __restrict__ ball, int* __restrict__ deg,
                       char* __restrict__ zbase) {
    int b = blockIdx.x, t = threadIdx.x;
    if (b < 960) {                      // w_ih: 384*640 = 960*256
        int i = b * 256 + t;
        w_ih_b[i] = f2b(w_ih[i]);
        return;
    }
    b -= 960;
    if (b < 192) {                      // w_hh: 384*128 = 192*256
        int i = b * 256 + t;
        w_hh_b[i] = f2b(w_hh[i]);
        return;
    }
    b -= 192;
    if (b < 128) {                      // we: 128*256 = 128*256
        int i = b * 256 + t;
        we_b[i] = f2b(we[i]);
        return;
    }
    b -= 128;
    if (b < 79) {                       // deg zero (20000 ints)
        int i = b * 256 + t;
        if (i < NNODE) deg[i] = 0;
        return;
    }
    b -= 79;
    if (b < 384) {                      // Wall build: idx over 768*128
        int idx = b * 256 + t;
        int row = idx >> 7;
        int k = idx & 127;
        float v;
        if (row < 128)      v = wq[row * 128 + k];
        else if (row < 256) v = wk_[(row - 128) * 128 + k];
        else if (row < 384) v = wv[(row - 256) * 128 + k];
        else if (row < 512) v = wskip[(row - 384) * 128 + k];
        else {
            int j = row - 512;
            float a = 0.f;
            for (int t2 = 0; t2 < 128; t2++) a += wq[t2 * 128 + k] * we[t2 * 256 + j];
            v = a;
        }
        Wallb[row * 128 + k] = f2b(v);
        if (k == 0) {
            float bb;
            if (row < 128)      bb = bq[row];
            else if (row < 256) bb = bk[row - 128];
            else if (row < 384) bb = bv[row - 256];
            else if (row < 512) bb = bskip[row - 384];
            else { int j = row - 512; float a = 0.f; for (int t2 = 0; t2 < 128; t2++) a += bq[t2] * we[t2 * 256 + j]; bb = a; }
            ball[row] = bb;
        }
        return;
    }
    b -= 384;
    // arena clears: rep (0xFF, 800256 B) then cnt+sums (0, 21771776 B), 16B chunks
    const int NFF = 50016;     // 800256/16
    const int NZ  = 1360736;   // (800256 + 20971520)/16
    uint4 ff = make_uint4(0xFFFFFFFFu, 0xFFFFFFFFu, 0xFFFFFFFFu, 0xFFFFFFFFu);
    uint4 zz = make_uint4(0u, 0u, 0u, 0u);
    int idx = b * 256 + t;
    int stride = 1024 * 256;
    uint4* pff = (uint4*)zbase;                 // rep_src + rep_dst
    uint4* pzz = (uint4*)(zbase + 800256);      // cnt_src + cnt_dst + sum_src + sum_dst
    for (int i = idx; i < NFF; i += stride) pff[i] = ff;
    for (int i = idx; i < NZ; i += stride) pzz[i] = zz;
}

// ---- fused rep/count tables + dst-degree histogram ----
__global__ void k_tables_deg(const int* __restrict__ src_ids, const int* __restrict__ dst_ids,
                             unsigned* rep_src, unsigned* rep_dst, int* cnt_src, int* cnt_dst,
                             const int* __restrict__ eidx, int* __restrict__ deg) {
    int b = blockIdx.x, t = threadIdx.x;
    if (b < 16) {
        int i = b * 256 + t;
        if (i >= EVT) return;
        int s = src_ids[i], d = dst_ids[i];
        atomicMin(&rep_src[s], (unsigned)i);
        atomicAdd(&cnt_src[s], 1);
        atomicMin(&rep_dst[d], (unsigned)i);
        atomicAdd(&cnt_dst[d], 1);
    } else {
        int j = (b - 16) * 256 + t;
        if (j >= NEDGE) return;
        atomicAdd(&deg[eidx[NEDGE + j]], 1);
    }
}

// ---- build messages; write Xgb/Hg/Hgb DIRECTLY (unique fast path);
//      atomics into sums only for dup ids (cnt>1, ~4%) ----
__global__ void k_message(const int* __restrict__ et_ids, const int* __restrict__ src_ids,
                          const float* __restrict__ src_mask, const int* __restrict__ dst_ids,
                          const float* __restrict__ dst_mask, const int* __restrict__ ev_eids,
                          const float* __restrict__ ev_emb, const float* __restrict__ ev_mask,
                          const float* __restrict__ ev_ts, const float* __restrict__ memory,
                          const float* __restrict__ last_update, const float* __restrict__ time_w,
                          const float* __restrict__ time_b, const unsigned* __restrict__ rep_src,
                          const unsigned* __restrict__ rep_dst, const int* __restrict__ cnt_src,
                          const int* __restrict__ cnt_dst, float* sum_src, float* sum_dst,
                          u16* __restrict__ Xgb, float* __restrict__ Hg, u16* __restrict__ Hgb) {
    int i = blockIdx.x;
    int c = threadIdx.x;
    int et = et_ids[i];
    float sm = src_mask[i], dm = dst_mask[i], em = ev_mask[i], ts = ev_ts[i];
    int sid = src_ids[i], did = dst_ids[i], eid = ev_eids[i];
    float isnode = (et == 3 || et == 4) ? 1.f : 0.f;
    float rel = ts - last_update[eid] * dm;
    float tval = ts * isnode + rel * dm;
    float tse = __cosf(tval * time_w[c] + time_b[c]) * em;
    float typ = (float)et;
    float sv_raw = memory[(size_t)sid * HID + c];
    float dv_raw = memory[(size_t)did * HID + c];
    float sv = sv_raw * sm;
    float dv = dv_raw * dm;
    float ev = ev_emb[(size_t)i * HID + c];
    // Hg/Hgb (unmasked memory rows, pre-update)
    Hg[(size_t)i * HID + c] = sv_raw;
    Hgb[(size_t)i * HID + c] = f2b(sv_raw);
    Hg[(size_t)(EVT + i) * HID + c] = dv_raw;
    Hgb[(size_t)(EVT + i) * HID + c] = f2b(dv_raw);
    // src-side message values
    float s0 = typ * em, s1 = sv * em, s2 = dv * em, s3 = tse * em, s4 = ev * em;
    u16* xs = Xgb + (size_t)i * 640;
    xs[c] = f2b(s0); xs[128 + c] = f2b(s1); xs[256 + c] = f2b(s2);
    xs[384 + c] = f2b(s3); xs[512 + c] = f2b(s4);
    if (cnt_src[sid] > 1) {
        float* ps = sum_src + (size_t)rep_src[sid] * 640;
        atomicAdd(ps + c, s0);
        atomicAdd(ps + 128 + c, s1);
        atomicAdd(ps + 256 + c, s2);
        atomicAdd(ps + 384 + c, s3);
        atomicAdd(ps + 512 + c, s4);
    }
    // dst-side message values
    float d0 = typ * dm, d1 = dv * dm, d2 = sv * dm, d3 = tse * dm, d4 = ev * dm;
    u16* xd = Xgb + (size_t)(EVT + i) * 640;
    xd[c] = f2b(d0); xd[128 + c] = f2b(d1); xd[256 + c] = f2b(d2);
    xd[384 + c] = f2b(d3); xd[512 + c] = f2b(d4);
    if (cnt_dst[did] > 1) {
        float* pd = sum_dst + (size_t)rep_dst[did] * 640;
        atomicAdd(pd + c, d0);
        atomicAdd(pd + 128 + c, d1);
        atomicAdd(pd + 256 + c, d2);
        atomicAdd(pd + 384 + c, d3);
        atomicAdd(pd + 512 + c, d4);
    }
}

// ---- fixup: rows whose id has cnt>1 get the group mean (early-exit for ~96%) ----
__global__ void k_fix(const int* __restrict__ src_ids, const int* __restrict__ dst_ids,
                      const unsigned* __restrict__ rep_src, const unsigned* __restrict__ rep_dst,
                      const int* __restrict__ cnt_src, const int* __restrict__ cnt_dst,
                      const float* __restrict__ sum_src, const float* __restrict__ sum_dst,
                      u16* __restrict__ Xgb) {
    int r = blockIdx.x, c = threadIdx.x;
    const float* sum;
    int cnt;
    if (r < EVT) {
        int id = src_ids[r];
        cnt = cnt_src[id];
        if (cnt < 2) return;
        sum = sum_src + (size_t)rep_src[id] * 640;
    } else {
        int id = dst_ids[r - EVT];
        cnt = cnt_dst[id];
        if (cnt < 2) return;
        sum = sum_dst + (size_t)rep_dst[id] * 640;
    }
    float inv = 1.f / (float)cnt;
    u16* x = Xgb + (size_t)r * 640;
#pragma unroll
    for (int y = 0; y < 5; ++y)
        x[y * 128 + c] = f2b(sum[y * 128 + c] * inv);
}

// ---- MFMA bf16 GEMM tile body: C[M,N] (+)= A[M,K] @ W[N,K]^T (+bias) ----
// 128x128 tile, 256 threads (4 waves, each 64x64), BK=32, mfma_f32_16x16x32_bf16.
// When KVb != nullptr, cols 128..384 are emitted ONLY as bf16 (f32 store is dead).
__device__ __forceinline__ void gemm_tile(const u16* __restrict__ A, const u16* __restrict__ W,
                                          const float* __restrict__ bias, float* __restrict__ C,
                                          u16* __restrict__ KVb, int M, int N, int K, int acc,
                                          u16* Als, u16* Wls) {
    int tid = threadIdx.x;
    int bm = blockIdx.x * 128, bn = blockIdx.y * 128;
    int wave = tid >> 6, lane = tid & 63;
    int wm = (wave & 1) * 64, wn = (wave >> 1) * 64;
    int l15 = lane & 15, quad = lane >> 4;
    f32x4 accf[4][4] = {};
    for (int k0 = 0; k0 < K; k0 += 32) {
#pragma unroll
        for (int h = 0; h < 2; ++h) {
            int ch = tid + h * 256;
            int row = ch >> 2, kc = (ch & 3) * 8;
            int gr = bm + row;
            float4 av = make_float4(0.f, 0.f, 0.f, 0.f);
            if (gr < M) av = *(const float4*)(A + (size_t)gr * K + k0 + kc);
            *(float4*)&Als[row * 40 + kc] = av;
            int wr = bn + row;
            float4 wv_ = *(const float4*)(W + (size_t)wr * K + k0 + kc);
            *(float4*)&Wls[row * 40 + kc] = wv_;
        }
        __syncthreads();
        bf16x8 af[4], bfr[4];
#pragma unroll
        for (int r = 0; r < 4; ++r)
            af[r] = *(const bf16x8*)&Als[(wm + r * 16 + l15) * 40 + quad * 8];
#pragma unroll
        for (int c2 = 0; c2 < 4; ++c2)
            bfr[c2] = *(const bf16x8*)&Wls[(wn + c2 * 16 + l15) * 40 + quad * 8];
#pragma unroll
        for (int r = 0; r < 4; ++r)
#pragma unroll
            for (int c2 = 0; c2 < 4; ++c2)
                accf[r][c2] = __builtin_amdgcn_mfma_f32_16x16x32_bf16(af[r], bfr[c2], accf[r][c2], 0, 0, 0);
        __syncthreads();
    }
#pragma unroll
    for (int r = 0; r < 4; ++r) {
#pragma unroll
        for (int c2 = 0; c2 < 4; ++c2) {
            int ncol = bn + wn + c2 * 16 + l15;
            float bv = bias ? bias[ncol] : 0.f;
#pragma unroll
            for (int reg = 0; reg < 4; ++reg) {
                int mrow = bm + wm + r * 16 + quad * 4 + reg;
                if (mrow >= M) continue;
                float v = accf[r][c2][reg] + bv;
                if (KVb && ncol >= 128 && ncol < 384) {
                    KVb[(size_t)mrow * 256 + (ncol - 128)] = f2b(v);
                } else {
                    if (acc) v += C[(size_t)mrow * N + ncol];
                    C[(size_t)mrow * N + ncol] = v;
                }
            }
        }
    }
}

__global__ __launch_bounds__(256) void k_gemm_mfma(const u16* __restrict__ A,
                                                   const u16* __restrict__ W,
                                                   const float* __restrict__ bias,
                                                   float* __restrict__ C,
                                                   u16* __restrict__ KVb,
                                                   int M, int N, int K, int acc) {
    __shared__ u16 Als[128 * 40];
    __shared__ u16 Wls[128 * 40];
    gemm_tile(A, W, bias, C, KVb, M, N, K, acc, Als, Wls);
}

// ---- fused event GEMMs: z=0 -> Gi (K=640), z=1 -> Gh (K=128) ----
__global__ __launch_bounds__(256) void k_gemm_dual(const u16* __restrict__ A0, const u16* __restrict__ W0,
                                                   const float* __restrict__ b0, float* __restrict__ C0,
                                                   const u16* __restrict__ A1, const u16* __restrict__ W1,
                                                   const float* __restrict__ b1, float* __restrict__ C1) {
    __shared__ u16 Als[128 * 40];
    __shared__ u16 Wls[128 * 40];
    if (blockIdx.z == 0) gemm_tile(A0, W0, b0, C0, nullptr, 2 * EVT, 384, 640, 0, Als, Wls);
    else                 gemm_tile(A1, W1, b1, C1, nullptr, 2 * EVT, 384, 128, 0, Als, Wls);
}

// ---- fused GRU gate combine + scatter-to-memory (dst overrides src) ----
// Reference semantics: memory[src_ids] = new_src; then memory[dst_ids] = new_dst.
// So a src-row write is only visible if its id never appears as a dst id
// (rep_dst[id] == ~0u). Duplicates within a side carry identical values.
__global__ void k_gru_scatter(const float* __restrict__ Gi, const float* __restrict__ Gh,
                              const float* __restrict__ Hg, const int* __restrict__ src_ids,
                              const int* __restrict__ dst_ids, const unsigned* __restrict__ rep_dst,
                              float* __restrict__ memory) {
    int r = blockIdx.x, c = threadIdx.x;
    const float* gi = Gi + (size_t)r * 384;
    const float* gh = Gh + (size_t)r * 384;
    float rg = sigmoidf_(gi[c] + gh[c]);
    float z  = sigmoidf_(gi[128 + c] + gh[128 + c]);
    float n  = tanhf(gi[256 + c] + rg * gh[256 + c]);
    float h0 = Hg[(size_t)r * HID + c];
    float h  = (1.f - z) * n + z * h0;
    if (r < EVT) {
        int sid = src_ids[r];
        if (rep_dst[sid] == 0xFFFFFFFFu) memory[(size_t)sid * HID + c] = h;
    } else {
        int did = dst_ids[r - EVT];
        memory[(size_t)did * HID + c] = h;
    }
}

__global__ void k_x(const int* __restrict__ node_ids, const float* __restrict__ nf,
                    const float* __restrict__ memory, u16* __restrict__ Xb) {
    int p = blockIdx.x, c = threadIdx.x;
    int nid = node_ids[p];
    Xb[(size_t)p * HID + c] = f2b(nf[(size_t)nid * HID + c] + memory[(size_t)nid * HID + c]);
}

// ---- single-block exclusive scan over 20000 degrees (int4-wide, 5 iterations) ----
__global__ __launch_bounds__(1024) void k_scan_one(const int* __restrict__ deg,
                                                   int* __restrict__ offs, int* __restrict__ cursor) {
    __shared__ int wsum[16];
    int t = threadIdx.x, lane = t & 63, w = t >> 6;
    int carry = 0;
    const int N4 = NNODE / 4;   // 5000
    for (int base = 0; base < N4; base += 1024) {
        int i4 = base + t;
        int4 v = make_int4(0, 0, 0, 0);
        if (i4 < N4) v = ((const int4*)deg)[i4];
        int s = v.x + v.y + v.z + v.w;
        int x = s;
#pragma unroll
        for (int d = 1; d < 64; d <<= 1) { int y = __shfl_up(x, d, 64); if (lane >= d) x += y; }
        if (lane == 63) wsum[w] = x;
        __syncthreads();
        int add = 0, tot = 0;
        for (int k2 = 0; k2 < 16; ++k2) { int ss = wsum[k2]; if (k2 < w) add += ss; tot += ss; }
        if (i4 < N4) {
            int e = carry + add + x - s;
            int4 o;
            o.x = e;
            o.y = e + v.x;
            o.z = o.y + v.y;
            o.w = o.z + v.z;
            ((int4*)offs)[i4] = o;
            ((int4*)cursor)[i4] = o;
        }
        carry += tot;
        __syncthreads();
    }
    if (t == 0) offs[NNODE] = NEDGE;
}

__global__ void k_sortscat(const int* __restrict__ eidx, int* __restrict__ cursor,
                           int* __restrict__ sorted) {
    int j = blockIdx.x * blockDim.x + threadIdx.x;
    if (j >= NEDGE) return;
    int d = eidx[NEDGE + j];
    int pos = atomicAdd(&cursor[d], 1);
    sorted[pos] = j;
}

// ---- fused per-node attention: 4-edge batched online softmax ----
__global__ __launch_bounds__(256) void k_node(const float* __restrict__ QK,
        const u16* __restrict__ KVb, const int* __restrict__ offs,
        const int* __restrict__ sorted, const int* __restrict__ eidx,
        const int* __restrict__ edge_ids, const float* __restrict__ last_update,
        const float* __restrict__ time_w, const float* __restrict__ time_b,
        const float* __restrict__ ef, const int* __restrict__ tptr,
        float* __restrict__ out, u16* __restrict__ saccb) {
    int wave = threadIdx.x >> 6, lane = threadIdx.x & 63;
    int n = blockIdx.x * 4 + wave;
    int c = 2 * lane;
    const float* base = QK + (size_t)n * 768;
    float2 qd   = *(const float2*)(base + c);
    float2 skip = *(const float2*)(base + 384 + c);
    float2 qet  = *(const float2*)(base + 512 + c);
    float2 qef  = *(const float2*)(base + 640 + c);
    float2 tw   = *(const float2*)(time_w + c);
    float2 tb   = *(const float2*)(time_b + c);
    float tf = (float)(*tptr);
    int start = offs[n], end = offs[n + 1];
    int deg = end - start;
    if (deg == 0) {
        *(float2*)(out + (size_t)n * HID + c) = skip;
        *(unsigned*)(saccb + (size_t)n * 256 + c) = 0u;
        *(unsigned*)(saccb + (size_t)n * 256 + 128 + c) = 0u;
        return;
    }
    float m = -1e30f, l_ = 0.f;
    float va0 = 0.f, va1 = 0.f, s00 = 0.f, s01 = 0.f, s10 = 0.f, s11 = 0.f;
    for (int cb = start; cb < end; cb += 64) {
        int cnt = end - cb; if (cnt > 64) cnt = 64;
        int s_l = 0, eid_l = 0; float rt_l = 0.f;
        if (lane < cnt) {
            int j = sorted[cb + lane];
            s_l = eidx[j];
            eid_l = edge_ids[j];
            rt_l = tf - last_update[eid_l];
        }
        for (int e0 = 0; e0 < cnt; e0 += 4) {
            float pv[4], cv0[4], cv1[4], vx[4], vy[4], ex[4], ey[4];
#pragma unroll
            for (int i = 0; i < 4; ++i) {
                int idx = e0 + i;
                int sel = (idx < cnt) ? idx : e0;
                int s   = __shfl(s_l, sel, 64);
                int eid = __shfl(eid_l, sel, 64);
                float rt = __shfl(rt_l, sel, 64);
                unsigned kvp = *(const unsigned*)(KVb + (size_t)s * 256 + c);
                unsigned vvp = *(const unsigned*)(KVb + (size_t)s * 256 + 128 + c);
                float2 ev = *(const float2*)(ef + (size_t)eid * HID + c);
                float k0f = b2f(kvp & 0xffffu), k1f = b2f(kvp >> 16);
                vx[i] = b2f(vvp & 0xffffu); vy[i] = b2f(vvp >> 16);
                cv0[i] = __cosf(rt * tw.x + tb.x);
                cv1[i] = __cosf(rt * tw.y + tb.y);
                ex[i] = ev.x; ey[i] = ev.y;
                pv[i] = qd.x * k0f + qd.y * k1f + qet.x * cv0[i] + qet.y * cv1[i]
                      + qef.x * ev.x + qef.y * ev.y;
            }
#pragma unroll
            for (int msk = 32; msk > 0; msk >>= 1) {
#pragma unroll
                for (int i = 0; i < 4; ++i) pv[i] += __shfl_xor(pv[i], msk, 64);
            }
            float al[4];
#pragma unroll
            for (int i = 0; i < 4; ++i)
                al[i] = (e0 + i < cnt) ? pv[i] * 0.08838834764831845f : -1e30f;
            float gm = fmaxf(fmaxf(al[0], al[1]), fmaxf(al[2], al[3]));
            if (gm > m) {
                float fac = __expf(m - gm);
                l_ *= fac; va0 *= fac; va1 *= fac;
                s00 *= fac; s01 *= fac; s10 *= fac; s11 *= fac;
                m = gm;
            }
#pragma unroll
            for (int i = 0; i < 4; ++i) {
                float w = __expf(al[i] - m);
                l_ += w;
                va0 += w * vx[i]; va1 += w * vy[i];
                s00 += w * cv0[i]; s01 += w * cv1[i];
                s10 += w * ex[i]; s11 += w * ey[i];
            }
        }
    }
    float inv = 1.f / fmaxf(l_, 1e-16f);
    float2 o; o.x = va0 * inv + skip.x; o.y = va1 * inv + skip.y;
    *(float2*)(out + (size_t)n * HID + c) = o;
    unsigned p0 = (unsigned)f2b(s00 * inv) | ((unsigned)f2b(s01 * inv) << 16);
    unsigned p1 = (unsigned)f2b(s10 * inv) | ((unsigned)f2b(s11 * inv) << 16);
    *(unsigned*)(saccb + (size_t)n * 256 + c) = p0;
    *(unsigned*)(saccb + (size_t)n * 256 + 128 + c) = p1;
}

extern "C" void kernel_launch(void* const* d_in, const int* in_sizes, int n_in,
                              void* d_out, int out_size, void* d_ws, size_t ws_size,
                              hipStream_t stream) {
    const int*   et_ids        = (const int*)d_in[0];
    const int*   src_ids       = (const int*)d_in[1];
    const float* src_mask      = (const float*)d_in[2];
    const int*   dst_ids       = (const int*)d_in[3];
    const float* dst_mask      = (const float*)d_in[4];
    const int*   ev_eids       = (const int*)d_in[5];
    const float* ev_emb        = (const float*)d_in[6];
    const float* ev_mask       = (const float*)d_in[7];
    const float* ev_ts         = (const float*)d_in[8];
    const int*   node_ids      = (const int*)d_in[9];
    const int*   edge_ids      = (const int*)d_in[10];
    const int*   edge_index    = (const int*)d_in[11];
    const int*   tptr          = (const int*)d_in[12];
    float*       memory        = (float*)d_in[13];
    const float* last_update   = (const float*)d_in[14];
    const float* node_features = (const float*)d_in[15];
    const float* edge_features = (const float*)d_in[16];
    const float* time_w        = (const float*)d_in[17];
    const float* time_b        = (const float*)d_in[18];
    const float* w_ih          = (const float*)d_in[19];
    const float* w_hh          = (const float*)d_in[20];
    const float* b_ih          = (const float*)d_in[21];
    const float* b_hh          = (const float*)d_in[22];
    const float* wq            = (const float*)d_in[23];
    const float* bq            = (const float*)d_in[24];
    const float* wk            = (const float*)d_in[25];
    const float* bk            = (const float*)d_in[26];
    const float* wv            = (const float*)d_in[27];
    const float* bv            = (const float*)d_in[28];
    const float* we            = (const float*)d_in[29];
    const float* wskip         = (const float*)d_in[30];
    const float* bskip         = (const float*)d_in[31];
    float* out = (float*)d_out;
    char*  wsb = (char*)d_ws;

    u16*   w_ih_b  = (u16*)(wsb + OFF_WIHB);
    u16*   w_hh_b  = (u16*)(wsb + OFF_WHHB);
    u16*   we_b    = (u16*)(wsb + OFF_WEB);
    u16*   Wallb   = (u16*)(wsb + OFF_WALLB);
    float* ball    = (float*)(wsb + OFF_BALL);
    unsigned* rep_src = (unsigned*)(wsb + OFF_REP_SRC);
    unsigned* rep_dst = (unsigned*)(wsb + OFF_REP_DST);
    int*   cnt_src = (int*)(wsb + OFF_CNT_SRC);
    int*   cnt_dst = (int*)(wsb + OFF_CNT_DST);
    float* sum_src = (float*)(wsb + OFF_SUM_SRC);
    float* sum_dst = (float*)(wsb + OFF_SUM_DST);
    u16*   Xgb     = (u16*)(wsb + OFF_XGB);
    float* Hg      = (float*)(wsb + OFF_HG);
    u16*   Hgb     = (u16*)(wsb + OFF_HGB);
    float* Gi      = (float*)(wsb + OFF_GI);
    float* Gh      = (float*)(wsb + OFF_GH);
    u16*   Xb      = (u16*)(wsb + OFF_XB);
    float* QKVSE   = (float*)(wsb + OFF_QKVSE);
    u16*   KVb     = (u16*)(wsb + OFF_KVB);
    int*   deg     = (int*)(wsb + OFF_DEG);
    int*   offs    = (int*)(wsb + OFF_OFFS);
    int*   cursor  = (int*)(wsb + OFF_CURSOR);
    int*   sorted  = (int*)(wsb + OFF_SORTED);
    u16*   saccb   = (u16*)(wsb + OFF_SACCB);

    // ---- weight prep + deg zero + arena clears (1 dispatch) ----
    k_prep<<<2767, 256, 0, stream>>>(w_ih, w_hh, we, wq, wk, wv, wskip, bq, bk, bv, bskip,
                                     w_ih_b, w_hh_b, we_b, Wallb, ball, deg, wsb + OFF_REP_SRC);
    // ---- event phase ----
    k_tables_deg<<<1266, 256, 0, stream>>>(src_ids, dst_ids, rep_src, rep_dst, cnt_src, cnt_dst,
                                           edge_index, deg);
    k_message<<<EVT, 128, 0, stream>>>(et_ids, src_ids, src_mask, dst_ids, dst_mask, ev_eids,
                                       ev_emb, ev_mask, ev_ts, memory, last_update, time_w, time_b,
                                       rep_src, rep_dst, cnt_src, cnt_dst, sum_src, sum_dst,
                                       Xgb, Hg, Hgb);
    k_fix<<<2 * EVT, 128, 0, stream>>>(src_ids, dst_ids, rep_src, rep_dst,
                                       cnt_src, cnt_dst, sum_src, sum_dst, Xgb);
    k_gemm_dual<<<dim3(64, 3, 2), 256, 0, stream>>>(Xgb, w_ih_b, b_ih, Gi,
                                                    Hgb, w_hh_b, b_hh, Gh);
    k_gru_scatter<<<2 * EVT, 128, 0, stream>>>(Gi, Gh, Hg, src_ids, dst_ids, rep_dst, memory);

    // ---- node phase ----
    k_x<<<NNODE, 128, 0, stream>>>(node_ids, node_features, memory, Xb);
    k_gemm_mfma<<<dim3(157, 6), 256, 0, stream>>>(Xb, Wallb, ball, QKVSE, KVb, NNODE, 768, 128, 0);
    k_scan_one<<<1, 1024, 0, stream>>>(deg, offs, cursor);
    k_sortscat<<<1250, 256, 0, stream>>>(edge_index, cursor, sorted);
    k_node<<<NNODE / 4, 256, 0, stream>>>(QKVSE, KVb, offs, sorted, edge_index, edge_ids,
                                          last_update, time_w, time_b, edge_features, tptr,
                                          out, saccb);
    k_gemm_mfma<<<dim3(157, 1), 256, 0, stream>>>(saccb, we_b, nullptr, out, nullptr, NNODE, 128, 256, 1);
}

// Round 3
// 490.086 us; speedup vs baseline: 1.1372x; 1.0406x over previous
//
#include <hip/hip_runtime.h>
#include <math.h>

#define HID   128
#define MAXN  100000
#define MAXE  300000
#define EVT   4096
#define NNODE 20000
#define NEDGE 320000

typedef unsigned short u16;
typedef __attribute__((ext_vector_type(8))) short bf16x8;
typedef __attribute__((ext_vector_type(4))) float f32x4;

// ---------------- workspace layout (bytes) ----------------
// PERSIST (weights, live for whole launch)
#define OFF_WIHB      0u            // 384*640 bf16
#define OFF_WHHB      491520u      // 384*128 bf16
#define OFF_WEB       589824u      // 128*256 bf16
#define OFF_WALLB     655360u      // 768*128 bf16
#define OFF_BALL      851968u      // 768 f32
#define BASE2         855040u
// EVENT arena (from BASE2)
#define OFF_HEAD_SRC  (BASE2 + 0u)          // MAXN i32 (0xFF init)
#define OFF_HEAD_DST  (BASE2 + 400128u)     // MAXN i32 (0xFF init)
#define OFF_CNT_SRC   (BASE2 + 800256u)     // MAXN i32 (0 init)
#define OFF_CNT_DST   (BASE2 + 1200384u)    // MAXN i32 (0 init)
#define OFF_CHAIN_SRC (BASE2 + 1600512u)    // EVT i32 (no init)
#define OFF_CHAIN_DST (BASE2 + 1616896u)    // EVT i32 (no init)
#define OFF_XGB       (BASE2 + 22572032u)   // 8192*640 bf16
#define OFF_HG        (BASE2 + 33057792u)   // 8192*128 f32
#define OFF_HGB       (BASE2 + 37252096u)   // 8192*128 bf16
#define OFF_GI        (BASE2 + 39349248u)   // 8192*384 f32
#define OFF_GH        (BASE2 + 51932160u)   // 8192*384 f32
// NODE arena (aliases EVENT arena tail; event phase fully complete first)
#define OFF_XB        (BASE2 + 1703936u)    // 20000*128 bf16 (after chains)
#define OFF_QKVSE     (BASE2 + 7000064u)    // 20000*768 f32  (before XGB? no...)
// keep node arena in previously-safe region (after GH not needed once node phase starts)
#undef OFF_XB
#undef OFF_QKVSE
#define OFF_XB        (BASE2 + 1703936u)    // 20000*128 bf16 = 5,120,000 B
#define OFF_QKVSE     (BASE2 + 6823936u)    // 20000*768 f32 = 61,440,000 B
#define OFF_KVB       (BASE2 + 68263936u)   // 20000*256 bf16 = 10,240,000 B
#define OFF_DEG       (BASE2 + 78503936u)   // 20000 i32
#define OFF_OFFS      (BASE2 + 78584064u)   // 20001 i32
#define OFF_CURSOR    (BASE2 + 78664192u)   // 20000 i32
#define OFF_SORTED    (BASE2 + 78744320u)   // 320000 i32
#define OFF_SACCB     (BASE2 + 80024320u)   // 20000*256 bf16
// NOTE: node arena (XB/QKVSE/...) overlaps GI/GH/XGB/HG regions only AFTER the
// event phase has fully consumed them:
//  - XB (starts 1.7MB) overlaps nothing below 6.8MB except chains (done) -- safe
//  - QKVSE [6.8MB,68.2MB) overlaps XGB/HG/HGB/GI/GH -- all dead once k_gru_scatter ran
//    (QKVSE written at dispatch 7, after k_gru_scatter at dispatch 5) -- safe
// deg/offs/cursor/sorted live at [78.5MB..) -- no overlap with event arena.
// peak ~90.3 MB

__device__ __forceinline__ float sigmoidf_(float x) { return 1.f / (1.f + __expf(-x)); }
__device__ __forceinline__ u16 f2b(float f) {
    unsigned u = __float_as_uint(f);
    unsigned r = (u + 0x7fffu + ((u >> 16) & 1u)) >> 16;
    return (u16)r;
}
__device__ __forceinline__ float b2f(unsigned h) { return __uint_as_float(h << 16); }

// ---- fused weight prep: 3 bf16 converts + Wall build + deg zero + table clears ----
// sections: [0,960) w_ih | [960,1152) w_hh | [1152,1280) we | [1280,1359) deg
//           [1359,1743) Wall | [1743,2000) head-fill + cnt-zero (grid-stride)
__global__ void k_prep(const float* __restrict__ w_ih, const float* __restrict__ w_hh,
                       const float* __restrict__ we,
                       const float* __restrict__ wq, const float* __restrict__ wk_,
                       const float* __restrict__ wv, const float* __restrict__ wskip,
                       const float* __restrict__ bq, const float* __restrict__ bk,
                       const float* __restrict__ bv, const float* __restrict__ bskip,
                       u16* __restrict__ w_ih_b, u16* __restrict__ w_hh_b,
                       u16* __restrict__ we_b, u16* __restrict__ Wallb,
                       float* __restrict__ ball, int* __restrict__ deg,
                       char* __restrict__ zbase) {
    int b = blockIdx.x, t = threadIdx.x;
    if (b < 960) {                      // w_ih: 384*640 = 960*256
        int i = b * 256 + t;
        w_ih_b[i] = f2b(w_ih[i]);
        return;
    }
    b -= 960;
    if (b < 192) {                      // w_hh: 384*128 = 192*256
        int i = b * 256 + t;
        w_hh_b[i] = f2b(w_hh[i]);
        return;
    }
    b -= 192;
    if (b < 128) {                      // we: 128*256 = 128*256
        int i = b * 256 + t;
        we_b[i] = f2b(we[i]);
        return;
    }
    b -= 128;
    if (b < 79) {                       // deg zero (20000 ints)
        int i = b * 256 + t;
        if (i < NNODE) deg[i] = 0;
        return;
    }
    b -= 79;
    if (b < 384) {                      // Wall build: idx over 768*128
        int idx = b * 256 + t;
        int row = idx >> 7;
        int k = idx & 127;
        float v;
        if (row < 128)      v = wq[row * 128 + k];
        else if (row < 256) v = wk_[(row - 128) * 128 + k];
        else if (row < 384) v = wv[(row - 256) * 128 + k];
        else if (row < 512) v = wskip[(row - 384) * 128 + k];
        else {
            int j = row - 512;
            float a = 0.f;
            for (int t2 = 0; t2 < 128; t2++) a += wq[t2 * 128 + k] * we[t2 * 256 + j];
            v = a;
        }
        Wallb[row * 128 + k] = f2b(v);
        if (k == 0) {
            float bb;
            if (row < 128)      bb = bq[row];
            else if (row < 256) bb = bk[row - 128];
            else if (row < 384) bb = bv[row - 256];
            else if (row < 512) bb = bskip[row - 384];
            else { int j = row - 512; float a = 0.f; for (int t2 = 0; t2 < 128; t2++) a += bq[t2] * we[t2 * 256 + j]; bb = a; }
            ball[row] = bb;
        }
        return;
    }
    b -= 384;
    // table clears: heads (0xFF, 800256 B) then cnts (0, 800256 B), 16B chunks
    const int NFF = 50016;     // 800256/16
    uint4 ff = make_uint4(0xFFFFFFFFu, 0xFFFFFFFFu, 0xFFFFFFFFu, 0xFFFFFFFFu);
    uint4 zz = make_uint4(0u, 0u, 0u, 0u);
    int idx = b * 256 + t;
    int stride = 257 * 256;
    uint4* pff = (uint4*)zbase;                 // head_src + head_dst
    uint4* pzz = (uint4*)(zbase + 800256);      // cnt_src + cnt_dst
    for (int i = idx; i < NFF; i += stride) pff[i] = ff;
    for (int i = idx; i < NFF; i += stride) pzz[i] = zz;
}

// ---- fused: messages (direct Xgb/Hg/Hgb write) + id tables/chains + dst-deg hist ----
// sections: [0,4096) message rows | [4096,4128) tables | [4128,6628) deg hist
__global__ void k_msg_tables(const int* __restrict__ et_ids, const int* __restrict__ src_ids,
                          const float* __restrict__ src_mask, const int* __restrict__ dst_ids,
                          const float* __restrict__ dst_mask, const int* __restrict__ ev_eids,
                          const float* __restrict__ ev_emb, const float* __restrict__ ev_mask,
                          const float* __restrict__ ev_ts, const float* __restrict__ memory,
                          const float* __restrict__ last_update, const float* __restrict__ time_w,
                          const float* __restrict__ time_b,
                          int* __restrict__ head_src, int* __restrict__ head_dst,
                          int* __restrict__ cnt_src, int* __restrict__ cnt_dst,
                          int* __restrict__ chain_src, int* __restrict__ chain_dst,
                          const int* __restrict__ eidx, int* __restrict__ deg,
                          u16* __restrict__ Xgb, float* __restrict__ Hg, u16* __restrict__ Hgb) {
    int b = blockIdx.x, t = threadIdx.x;
    if (b >= EVT) {
        int bb = b - EVT;
        if (bb < 32) {                       // tables: 4096 events
            int i = bb * 128 + t;
            int s = src_ids[i], d = dst_ids[i];
            chain_src[i] = atomicExch(&head_src[s], i);
            atomicAdd(&cnt_src[s], 1);
            chain_dst[i] = atomicExch(&head_dst[d], i);
            atomicAdd(&cnt_dst[d], 1);
        } else {                             // deg hist: 320000 edges
            int j = (bb - 32) * 128 + t;
            atomicAdd(&deg[eidx[NEDGE + j]], 1);
        }
        return;
    }
    int i = b;
    int c = t;
    int et = et_ids[i];
    float sm = src_mask[i], dm = dst_mask[i], em = ev_mask[i], ts = ev_ts[i];
    int sid = src_ids[i], did = dst_ids[i], eid = ev_eids[i];
    float isnode = (et == 3 || et == 4) ? 1.f : 0.f;
    float rel = ts - last_update[eid] * dm;
    float tval = ts * isnode + rel * dm;
    float tse = __cosf(tval * time_w[c] + time_b[c]) * em;
    float typ = (float)et;
    float sv_raw = memory[(size_t)sid * HID + c];
    float dv_raw = memory[(size_t)did * HID + c];
    float sv = sv_raw * sm;
    float dv = dv_raw * dm;
    float ev = ev_emb[(size_t)i * HID + c];
    // Hg/Hgb (unmasked memory rows, pre-update)
    Hg[(size_t)i * HID + c] = sv_raw;
    Hgb[(size_t)i * HID + c] = f2b(sv_raw);
    Hg[(size_t)(EVT + i) * HID + c] = dv_raw;
    Hgb[(size_t)(EVT + i) * HID + c] = f2b(dv_raw);
    // src-side message values (dup rows fixed later by k_fix)
    u16* xs = Xgb + (size_t)i * 640;
    xs[c] = f2b(typ * em); xs[128 + c] = f2b(sv * em); xs[256 + c] = f2b(dv * em);
    xs[384 + c] = f2b(tse * em); xs[512 + c] = f2b(ev * em);
    // dst-side message values
    u16* xd = Xgb + (size_t)(EVT + i) * 640;
    xd[c] = f2b(typ * dm); xd[128 + c] = f2b(dv * dm); xd[256 + c] = f2b(sv * dm);
    xd[384 + c] = f2b(tse * dm); xd[512 + c] = f2b(ev * dm);
}

// ---- fixup: rows whose id has cnt>1 recompute the group mean via chain walk ----
__global__ void k_fix(const int* __restrict__ src_ids, const int* __restrict__ dst_ids,
                      const int* __restrict__ head_src, const int* __restrict__ head_dst,
                      const int* __restrict__ chain_src, const int* __restrict__ chain_dst,
                      const int* __restrict__ cnt_src, const int* __restrict__ cnt_dst,
                      const int* __restrict__ et_ids, const float* __restrict__ src_mask,
                      const float* __restrict__ dst_mask, const int* __restrict__ ev_eids,
                      const float* __restrict__ ev_emb, const float* __restrict__ ev_mask,
                      const float* __restrict__ ev_ts, const float* __restrict__ memory,
                      const float* __restrict__ last_update, const float* __restrict__ time_w,
                      const float* __restrict__ time_b, u16* __restrict__ Xgb) {
    int r = blockIdx.x, c = threadIdx.x;
    bool is_src = (r < EVT);
    int id = is_src ? src_ids[r] : dst_ids[r - EVT];
    int cnt = is_src ? cnt_src[id] : cnt_dst[id];
    if (cnt < 2) return;
    float own = memory[(size_t)id * HID + c];
    float tw = time_w[c], tb = time_b[c];
    float a0 = 0.f, a1 = 0.f, a2 = 0.f, a3 = 0.f, a4 = 0.f;
    int j = is_src ? head_src[id] : head_dst[id];
    for (int k = 0; k < cnt; ++k) {
        int et = et_ids[j];
        float sm = src_mask[j], dm = dst_mask[j], em = ev_mask[j], ts = ev_ts[j];
        int eid = ev_eids[j];
        float isnode = (et == 3 || et == 4) ? 1.f : 0.f;
        float rel = ts - last_update[eid] * dm;
        float tval = ts * isnode + rel * dm;
        float tse = __cosf(tval * tw + tb);
        float ev = ev_emb[(size_t)j * HID + c];
        float typ = (float)et;
        if (is_src) {
            float sv = own * sm;                                  // memory[src]==own
            float dv = memory[(size_t)dst_ids[j] * HID + c] * dm;
            float tsm = tse * em;                                 // tse*em as in message
            a0 += typ * em; a1 += sv * em; a2 += dv * em;
            a3 += tsm * em; a4 += ev * em;
            j = chain_src[j];
        } else {
            float dv = own * dm;                                  // memory[dst]==own
            float sv = memory[(size_t)src_ids[j] * HID + c] * sm;
            float tsm = tse * em;
            a0 += typ * dm; a1 += dv * dm; a2 += sv * dm;
            a3 += tsm * dm; a4 += ev * dm;
            j = chain_dst[j];
        }
    }
    float inv = 1.f / (float)cnt;
    u16* x = Xgb + (size_t)r * 640;
    x[c] = f2b(a0 * inv); x[128 + c] = f2b(a1 * inv); x[256 + c] = f2b(a2 * inv);
    x[384 + c] = f2b(a3 * inv); x[512 + c] = f2b(a4 * inv);
}

// ---- MFMA bf16 GEMM tile body: C[M,N] (+)= A[M,K] @ W[N,K]^T (+bias) ----
// 128x128 tile, 256 threads (4 waves, each 64x64), BK=32, mfma_f32_16x16x32_bf16.
// When KVb != nullptr, cols 128..384 are emitted ONLY as bf16 (f32 store is dead).
__device__ __forceinline__ void gemm_tile(const u16* __restrict__ A, const u16* __restrict__ W,
                                          const float* __restrict__ bias, float* __restrict__ C,
                                          u16* __restrict__ KVb, int M, int N, int K, int acc,
                                          u16* Als, u16* Wls) {
    int tid = threadIdx.x;
    int bm = blockIdx.x * 128, bn = blockIdx.y * 128;
    int wave = tid >> 6, lane = tid & 63;
    int wm = (wave & 1) * 64, wn = (wave >> 1) * 64;
    int l15 = lane & 15, quad = lane >> 4;
    f32x4 accf[4][4] = {};
    for (int k0 = 0; k0 < K; k0 += 32) {
#pragma unroll
        for (int h = 0; h < 2; ++h) {
            int ch = tid + h * 256;
            int row = ch >> 2, kc = (ch & 3) * 8;
            int gr = bm + row;
            float4 av = make_float4(0.f, 0.f, 0.f, 0.f);
            if (gr < M) av = *(const float4*)(A + (size_t)gr * K + k0 + kc);
            *(float4*)&Als[row * 40 + kc] = av;
            int wr = bn + row;
            float4 wv_ = *(const float4*)(W + (size_t)wr * K + k0 + kc);
            *(float4*)&Wls[row * 40 + kc] = wv_;
        }
        __syncthreads();
        bf16x8 af[4], bfr[4];
#pragma unroll
        for (int r = 0; r < 4; ++r)
            af[r] = *(const bf16x8*)&Als[(wm + r * 16 + l15) * 40 + quad * 8];
#pragma unroll
        for (int c2 = 0; c2 < 4; ++c2)
            bfr[c2] = *(const bf16x8*)&Wls[(wn + c2 * 16 + l15) * 40 + quad * 8];
#pragma unroll
        for (int r = 0; r < 4; ++r)
#pragma unroll
            for (int c2 = 0; c2 < 4; ++c2)
                accf[r][c2] = __builtin_amdgcn_mfma_f32_16x16x32_bf16(af[r], bfr[c2], accf[r][c2], 0, 0, 0);
        __syncthreads();
    }
#pragma unroll
    for (int r = 0; r < 4; ++r) {
#pragma unroll
        for (int c2 = 0; c2 < 4; ++c2) {
            int ncol = bn + wn + c2 * 16 + l15;
            float bv = bias ? bias[ncol] : 0.f;
#pragma unroll
            for (int reg = 0; reg < 4; ++reg) {
                int mrow = bm + wm + r * 16 + quad * 4 + reg;
                if (mrow >= M) continue;
                float v = accf[r][c2][reg] + bv;
                if (KVb && ncol >= 128 && ncol < 384) {
                    KVb[(size_t)mrow * 256 + (ncol - 128)] = f2b(v);
                } else {
                    if (acc) v += C[(size_t)mrow * N + ncol];
                    C[(size_t)mrow * N + ncol] = v;
                }
            }
        }
    }
}

__global__ __launch_bounds__(256) void k_gemm_mfma(const u16* __restrict__ A,
                                                   const u16* __restrict__ W,
                                                   const float* __restrict__ bias,
                                                   float* __restrict__ C,
                                                   u16* __restrict__ KVb,
                                                   int M, int N, int K, int acc) {
    __shared__ u16 Als[128 * 40];
    __shared__ u16 Wls[128 * 40];
    gemm_tile(A, W, bias, C, KVb, M, N, K, acc, Als, Wls);
}

// ---- QKVSE GEMM with sortscat slice (y==6) ----
__global__ __launch_bounds__(256) void k_gemm_qkvse(const u16* __restrict__ A,
                                                    const u16* __restrict__ W,
                                                    const float* __restrict__ bias,
                                                    float* __restrict__ C,
                                                    u16* __restrict__ KVb,
                                                    const int* __restrict__ eidx,
                                                    int* __restrict__ cursor,
                                                    int* __restrict__ sorted) {
    __shared__ u16 Als[128 * 40];
    __shared__ u16 Wls[128 * 40];
    if (blockIdx.y == 6) {
        int j = blockIdx.x * 256 + threadIdx.x;
        for (; j < NEDGE; j += 157 * 256) {
            int d = eidx[NEDGE + j];
            int pos = atomicAdd(&cursor[d], 1);
            sorted[pos] = j;
        }
        return;
    }
    gemm_tile(A, W, bias, C, KVb, NNODE, 768, 128, 0, Als, Wls);
}

// ---- fused event GEMMs: z=0 -> Gi (K=640), z=1 -> Gh (K=128) ----
__global__ __launch_bounds__(256) void k_gemm_dual(const u16* __restrict__ A0, const u16* __restrict__ W0,
                                                   const float* __restrict__ b0, float* __restrict__ C0,
                                                   const u16* __restrict__ A1, const u16* __restrict__ W1,
                                                   const float* __restrict__ b1, float* __restrict__ C1) {
    __shared__ u16 Als[128 * 40];
    __shared__ u16 Wls[128 * 40];
    if (blockIdx.z == 0) gemm_tile(A0, W0, b0, C0, nullptr, 2 * EVT, 384, 640, 0, Als, Wls);
    else                 gemm_tile(A1, W1, b1, C1, nullptr, 2 * EVT, 384, 128, 0, Als, Wls);
}

// ---- fused GRU gate combine + scatter-to-memory (dst overrides src) ----
// Reference: memory[src_ids]=new_src then memory[dst_ids]=new_dst. A src-row
// write is visible only if its id never appears as a dst id (cnt_dst==0).
__global__ void k_gru_scatter(const float* __restrict__ Gi, const float* __restrict__ Gh,
                              const float* __restrict__ Hg, const int* __restrict__ src_ids,
                              const int* __restrict__ dst_ids, const int* __restrict__ cnt_dst,
                              float* __restrict__ memory) {
    int r = blockIdx.x, c = threadIdx.x;
    const float* gi = Gi + (size_t)r * 384;
    const float* gh = Gh + (size_t)r * 384;
    float rg = sigmoidf_(gi[c] + gh[c]);
    float z  = sigmoidf_(gi[128 + c] + gh[128 + c]);
    float n  = tanhf(gi[256 + c] + rg * gh[256 + c]);
    float h0 = Hg[(size_t)r * HID + c];
    float h  = (1.f - z) * n + z * h0;
    if (r < EVT) {
        int sid = src_ids[r];
        if (cnt_dst[sid] == 0) memory[(size_t)sid * HID + c] = h;
    } else {
        int did = dst_ids[r - EVT];
        memory[(size_t)did * HID + c] = h;
    }
}

// ---- node-feature build (blocks 0..2499, 8 rows each) + degree scan (block 2500) ----
__global__ __launch_bounds__(1024) void k_x_scan(const int* __restrict__ node_ids,
                                                 const float* __restrict__ nf,
                                                 const float* __restrict__ memory,
                                                 u16* __restrict__ Xb,
                                                 const int* __restrict__ deg,
                                                 int* __restrict__ offs,
                                                 int* __restrict__ cursor) {
    __shared__ int wsum[16];
    int p = blockIdx.x, t = threadIdx.x;
    if (p < 2500) {
        int row = p * 8 + (t >> 7), c = t & 127;
        int nid = node_ids[row];
        Xb[(size_t)row * HID + c] = f2b(nf[(size_t)nid * HID + c] + memory[(size_t)nid * HID + c]);
        return;
    }
    // exclusive scan over 20000 degrees (int4-wide, 5 iterations)
    int lane = t & 63, w = t >> 6;
    int carry = 0;
    const int N4 = NNODE / 4;   // 5000
    for (int base = 0; base < N4; base += 1024) {
        int i4 = base + t;
        int4 v = make_int4(0, 0, 0, 0);
        if (i4 < N4) v = ((const int4*)deg)[i4];
        int s = v.x + v.y + v.z + v.w;
        int x = s;
#pragma unroll
        for (int d = 1; d < 64; d <<= 1) { int y = __shfl_up(x, d, 64); if (lane >= d) x += y; }
        if (lane == 63) wsum[w] = x;
        __syncthreads();
        int add = 0, tot = 0;
        for (int k2 = 0; k2 < 16; ++k2) { int ss = wsum[k2]; if (k2 < w) add += ss; tot += ss; }
        if (i4 < N4) {
            int e = carry + add + x - s;
            int4 o;
            o.x = e;
            o.y = e + v.x;
            o.z = o.y + v.y;
            o.w = o.z + v.z;
            ((int4*)offs)[i4] = o;
            ((int4*)cursor)[i4] = o;
        }
        carry += tot;
        __syncthreads();
    }
    if (t == 0) offs[NNODE] = NEDGE;
}

// ---- fused per-node attention: 4-edge batched online softmax ----
__global__ __launch_bounds__(256) void k_node(const float* __restrict__ QK,
        const u16* __restrict__ KVb, const int* __restrict__ offs,
        const int* __restrict__ sorted, const int* __restrict__ eidx,
        const int* __restrict__ edge_ids, const float* __restrict__ last_update,
        const float* __restrict__ time_w, const float* __restrict__ time_b,
        const float* __restrict__ ef, const int* __restrict__ tptr,
        float* __restrict__ out, u16* __restrict__ saccb) {
    int wave = threadIdx.x >> 6, lane = threadIdx.x & 63;
    int n = blockIdx.x * 4 + wave;
    int c = 2 * lane;
    const float* base = QK + (size_t)n * 768;
    float2 qd   = *(const float2*)(base + c);
    float2 skip = *(const float2*)(base + 384 + c);
    float2 qet  = *(const float2*)(base + 512 + c);
    float2 qef  = *(const float2*)(base + 640 + c);
    float2 tw   = *(const float2*)(time_w + c);
    float2 tb   = *(const float2*)(time_b + c);
    float tf = (float)(*tptr);
    int start = offs[n], end = offs[n + 1];
    int deg = end - start;
    if (deg == 0) {
        *(float2*)(out + (size_t)n * HID + c) = skip;
        *(unsigned*)(saccb + (size_t)n * 256 + c) = 0u;
        *(unsigned*)(saccb + (size_t)n * 256 + 128 + c) = 0u;
        return;
    }
    float m = -1e30f, l_ = 0.f;
    float va0 = 0.f, va1 = 0.f, s00 = 0.f, s01 = 0.f, s10 = 0.f, s11 = 0.f;
    for (int cb = start; cb < end; cb += 64) {
        int cnt = end - cb; if (cnt > 64) cnt = 64;
        int s_l = 0, eid_l = 0; float rt_l = 0.f;
        if (lane < cnt) {
            int j = sorted[cb + lane];
            s_l = eidx[j];
            eid_l = edge_ids[j];
            rt_l = tf - last_update[eid_l];
        }
        for (int e0 = 0; e0 < cnt; e0 += 4) {
            float pv[4], cv0[4], cv1[4], vx[4], vy[4], ex[4], ey[4];
#pragma unroll
            for (int i = 0; i < 4; ++i) {
                int idx = e0 + i;
                int sel = (idx < cnt) ? idx : e0;
                int s   = __shfl(s_l, sel, 64);
                int eid = __shfl(eid_l, sel, 64);
                float rt = __shfl(rt_l, sel, 64);
                unsigned kvp = *(const unsigned*)(KVb + (size_t)s * 256 + c);
                unsigned vvp = *(const unsigned*)(KVb + (size_t)s * 256 + 128 + c);
                float2 ev = *(const float2*)(ef + (size_t)eid * HID + c);
                float k0f = b2f(kvp & 0xffffu), k1f = b2f(kvp >> 16);
                vx[i] = b2f(vvp & 0xffffu); vy[i] = b2f(vvp >> 16);
                cv0[i] = __cosf(rt * tw.x + tb.x);
                cv1[i] = __cosf(rt * tw.y + tb.y);
                ex[i] = ev.x; ey[i] = ev.y;
                pv[i] = qd.x * k0f + qd.y * k1f + qet.x * cv0[i] + qet.y * cv1[i]
                      + qef.x * ev.x + qef.y * ev.y;
            }
#pragma unroll
            for (int msk = 32; msk > 0; msk >>= 1) {
#pragma unroll
                for (int i = 0; i < 4; ++i) pv[i] += __shfl_xor(pv[i], msk, 64);
            }
            float al[4];
#pragma unroll
            for (int i = 0; i < 4; ++i)
                al[i] = (e0 + i < cnt) ? pv[i] * 0.08838834764831845f : -1e30f;
            float gm = fmaxf(fmaxf(al[0], al[1]), fmaxf(al[2], al[3]));
            if (gm > m) {
                float fac = __expf(m - gm);
                l_ *= fac; va0 *= fac; va1 *= fac;
                s00 *= fac; s01 *= fac; s10 *= fac; s11 *= fac;
                m = gm;
            }
#pragma unroll
            for (int i = 0; i < 4; ++i) {
                float w = __expf(al[i] - m);
                l_ += w;
                va0 += w * vx[i]; va1 += w * vy[i];
                s00 += w * cv0[i]; s01 += w * cv1[i];
                s10 += w * ex[i]; s11 += w * ey[i];
            }
        }
    }
    float inv = 1.f / fmaxf(l_, 1e-16f);
    float2 o; o.x = va0 * inv + skip.x; o.y = va1 * inv + skip.y;
    *(float2*)(out + (size_t)n * HID + c) = o;
    unsigned p0 = (unsigned)f2b(s00 * inv) | ((unsigned)f2b(s01 * inv) << 16);
    unsigned p1 = (unsigned)f2b(s10 * inv) | ((unsigned)f2b(s11 * inv) << 16);
    *(unsigned*)(saccb + (size_t)n * 256 + c) = p0;
    *(unsigned*)(saccb + (size_t)n * 256 + 128 + c) = p1;
}

extern "C" void kernel_launch(void* const* d_in, const int* in_sizes, int n_in,
                              void* d_out, int out_size, void* d_ws, size_t ws_size,
                              hipStream_t stream) {
    const int*   et_ids        = (const int*)d_in[0];
    const int*   src_ids       = (const int*)d_in[1];
    const float* src_mask      = (const float*)d_in[2];
    const int*   dst_ids       = (const int*)d_in[3];
    const float* dst_mask      = (const float*)d_in[4];
    const int*   ev_eids       = (const int*)d_in[5];
    const float* ev_emb        = (const float*)d_in[6];
    const float* ev_mask       = (const float*)d_in[7];
    const float* ev_ts         = (const float*)d_in[8];
    const int*   node_ids      = (const int*)d_in[9];
    const int*   edge_ids      = (const int*)d_in[10];
    const int*   edge_index    = (const int*)d_in[11];
    const int*   tptr          = (const int*)d_in[12];
    float*       memory        = (float*)d_in[13];
    const float* last_update   = (const float*)d_in[14];
    const float* node_features = (const float*)d_in[15];
    const float* edge_features = (const float*)d_in[16];
    const float* time_w        = (const float*)d_in[17];
    const float* time_b        = (const float*)d_in[18];
    const float* w_ih          = (const float*)d_in[19];
    const float* w_hh          = (const float*)d_in[20];
    const float* b_ih          = (const float*)d_in[21];
    const float* b_hh          = (const float*)d_in[22];
    const float* wq            = (const float*)d_in[23];
    const float* bq            = (const float*)d_in[24];
    const float* wk            = (const float*)d_in[25];
    const float* bk            = (const float*)d_in[26];
    const float* wv            = (const float*)d_in[27];
    const float* bv            = (const float*)d_in[28];
    const float* we            = (const float*)d_in[29];
    const float* wskip         = (const float*)d_in[30];
    const float* bskip         = (const float*)d_in[31];
    float* out = (float*)d_out;
    char*  wsb = (char*)d_ws;

    u16*   w_ih_b   = (u16*)(wsb + OFF_WIHB);
    u16*   w_hh_b   = (u16*)(wsb + OFF_WHHB);
    u16*   we_b     = (u16*)(wsb + OFF_WEB);
    u16*   Wallb    = (u16*)(wsb + OFF_WALLB);
    float* ball     = (float*)(wsb + OFF_BALL);
    int*   head_src = (int*)(wsb + OFF_HEAD_SRC);
    int*   head_dst = (int*)(wsb + OFF_HEAD_DST);
    int*   cnt_src  = (int*)(wsb + OFF_CNT_SRC);
    int*   cnt_dst  = (int*)(wsb + OFF_CNT_DST);
    int*   chain_src= (int*)(wsb + OFF_CHAIN_SRC);
    int*   chain_dst= (int*)(wsb + OFF_CHAIN_DST);
    u16*   Xgb      = (u16*)(wsb + OFF_XGB);
    float* Hg       = (float*)(wsb + OFF_HG);
    u16*   Hgb      = (u16*)(wsb + OFF_HGB);
    float* Gi       = (float*)(wsb + OFF_GI);
    float* Gh       = (float*)(wsb + OFF_GH);
    u16*   Xb       = (u16*)(wsb + OFF_XB);
    float* QKVSE    = (float*)(wsb + OFF_QKVSE);
    u16*   KVb      = (u16*)(wsb + OFF_KVB);
    int*   deg      = (int*)(wsb + OFF_DEG);
    int*   offs     = (int*)(wsb + OFF_OFFS);
    int*   cursor   = (int*)(wsb + OFF_CURSOR);
    int*   sorted   = (int*)(wsb + OFF_SORTED);
    u16*   saccb    = (u16*)(wsb + OFF_SACCB);

    // 1: weight prep + deg zero + table clears
    k_prep<<<2000, 256, 0, stream>>>(w_ih, w_hh, we, wq, wk, wv, wskip, bq, bk, bv, bskip,
                                     w_ih_b, w_hh_b, we_b, Wallb, ball, deg, wsb + OFF_HEAD_SRC);
    // 2: messages + tables/chains + deg hist
    k_msg_tables<<<6628, 128, 0, stream>>>(et_ids, src_ids, src_mask, dst_ids, dst_mask, ev_eids,
                                           ev_emb, ev_mask, ev_ts, memory, last_update, time_w, time_b,
                                           head_src, head_dst, cnt_src, cnt_dst, chain_src, chain_dst,
                                           edge_index, deg, Xgb, Hg, Hgb);
    // 3: dup-group mean fixup
    k_fix<<<2 * EVT, 128, 0, stream>>>(src_ids, dst_ids, head_src, head_dst, chain_src, chain_dst,
                                       cnt_src, cnt_dst, et_ids, src_mask, dst_mask, ev_eids,
                                       ev_emb, ev_mask, ev_ts, memory, last_update, time_w, time_b,
                                       Xgb);
    // 4: event GEMMs
    k_gemm_dual<<<dim3(64, 3, 2), 256, 0, stream>>>(Xgb, w_ih_b, b_ih, Gi,
                                                    Hgb, w_hh_b, b_hh, Gh);
    // 5: GRU + memory scatter
    k_gru_scatter<<<2 * EVT, 128, 0, stream>>>(Gi, Gh, Hg, src_ids, dst_ids, cnt_dst, memory);
    // 6: node features + degree scan
    k_x_scan<<<2501, 1024, 0, stream>>>(node_ids, node_features, memory, Xb, deg, offs, cursor);
    // 7: QKVSE GEMM + sortscat slice
    k_gemm_qkvse<<<dim3(157, 7), 256, 0, stream>>>(Xb, Wallb, ball, QKVSE, KVb,
                                                   edge_index, cursor, sorted);
    // 8: per-node attention
    k_node<<<NNODE / 4, 256, 0, stream>>>(QKVSE, KVb, offs, sorted, edge_index, edge_ids,
                                          last_update, time_w, time_b, edge_features, tptr,
                                          out, saccb);
    // 9: final edge-feature GEMM (accumulate into out)
    k_gemm_mfma<<<dim3(157, 1), 256, 0, stream>>>(saccb, we_b, nullptr, out, nullptr, NNODE, 128, 256, 1);
}